// Round 1
// baseline (682.414 us; speedup 1.0000x reference)
//
#include <hip/hip_runtime.h>
#include <hip/hip_bf16.h>
#include <hip/hip_fp16.h>

// Swin-V2 window attention, MI355X (gfx950).
// Pipeline: K0 setup (f16 weights + bias+mask table) -> K1 QKV GEMM (f16 MFMA)
// -> K2 per-window attention + proj (f16 MFMA, f32 softmax).
// Workspace requirement: ~236 MB (qkv16 intermediate = 231 MB).

#define NTOK 49
#define DIM 192
#define NH 6
#define HD 32
#define BATCH 4096
#define NWIN 64
#define M_TOTAL (BATCH * NTOK)  // 200704

typedef __attribute__((ext_vector_type(4))) float f32x4;
typedef __attribute__((ext_vector_type(8))) _Float16 f16x8;

// ws layout (bytes)
#define W1_OFF 0                         // [576][192] f16
#define W2_OFF (576 * 192 * 2)           // [192][192] f16
#define BM_OFF (W2_OFF + 192 * 192 * 2)  // [64][6][49][49] f32 = 3.69 MB
#define QKV_OFF 4194304                  // [3][B][H][49][32] f16 = 231 MB

#define MFMA16(a, b, c) __builtin_amdgcn_mfma_f32_16x16x32_f16(a, b, c, 0, 0, 0)

__global__ __launch_bounds__(256) void k_setup(
    const float* __restrict__ qkv_w, const float* __restrict__ proj_w,
    const float* __restrict__ mask, const float* __restrict__ table,
    const int* __restrict__ rel_index,
    _Float16* __restrict__ W1, _Float16* __restrict__ W2, float* __restrict__ bm) {
  int idx = blockIdx.x * 256 + threadIdx.x;
  if (idx < 576 * 192) W1[idx] = (_Float16)qkv_w[idx];
  if (idx < 192 * 192) W2[idx] = (_Float16)proj_w[idx];
  if (idx < NWIN * NH * 2401) {
    int wh = idx / 2401, ij = idx % 2401;
    int widx = wh / NH, h = wh - widx * NH;
    bm[idx] = table[rel_index[ij] * NH + h] + mask[widx * 2401 + ij];
  }
}

// K1: qkv = x @ qkv_w^T + b  -> q,k,v f16 [3][B][H][49][32]
__global__ __launch_bounds__(256) void k_qkv(
    const float* __restrict__ x, const _Float16* __restrict__ W1,
    const float* __restrict__ qkv_b, _Float16* __restrict__ qkv16) {
  const int lane = threadIdx.x & 63;
  const int w = threadIdx.x >> 6;
  const int rowbase = blockIdx.x * 128 + w * 32;
  const int lr = lane & 15;
  const int lk = (lane >> 4) * 8;

  // A fragments: 2 row-tiles x 6 K-frags, f32 -> f16
  f16x8 a[2][6];
#pragma unroll
  for (int rt = 0; rt < 2; ++rt) {
    const float* xr = x + (size_t)(rowbase + rt * 16 + lr) * DIM + lk;
#pragma unroll
    for (int kf = 0; kf < 6; ++kf) {
      f32x4 lo = *(const f32x4*)(xr + kf * 32);
      f32x4 hi = *(const f32x4*)(xr + kf * 32 + 4);
      f16x8 v;
      v[0] = (_Float16)lo[0]; v[1] = (_Float16)lo[1];
      v[2] = (_Float16)lo[2]; v[3] = (_Float16)lo[3];
      v[4] = (_Float16)hi[0]; v[5] = (_Float16)hi[1];
      v[6] = (_Float16)hi[2]; v[7] = (_Float16)hi[3];
      a[rt][kf] = v;
    }
  }
  // store row offsets (D rows: (lane>>4)*4 + reg)
  int rowoff[2][4];
#pragma unroll
  for (int rt = 0; rt < 2; ++rt)
#pragma unroll
    for (int r = 0; r < 4; ++r) {
      int row = rowbase + rt * 16 + (lane >> 4) * 4 + r;
      int b = row / 49, n = row - b * 49;
      rowoff[rt][r] = b * (NH * NTOK * HD) + n * HD;
    }

  for (int ct = 0; ct < 36; ++ct) {
    f16x8 bw[6];
    const _Float16* wp = W1 + (ct * 16 + lr) * DIM + lk;
#pragma unroll
    for (int kf = 0; kf < 6; ++kf) bw[kf] = *(const f16x8*)(wp + kf * 32);
    f32x4 acc0 = {0.f, 0.f, 0.f, 0.f}, acc1 = {0.f, 0.f, 0.f, 0.f};
#pragma unroll
    for (int kf = 0; kf < 6; ++kf) {
      acc0 = MFMA16(a[0][kf], bw[kf], acc0);
      acc1 = MFMA16(a[1][kf], bw[kf], acc1);
    }
    int col = ct * 16 + lr;  // D col = lane&15
    float bias = qkv_b[col];
    int s = col / DIM, rem = col - s * DIM;
    int h = rem >> 5, d = rem & 31;
    size_t colpart = (size_t)s * BATCH * NH * NTOK * HD + (size_t)h * (NTOK * HD) + d;
    _Float16* qp = qkv16 + colpart;
#pragma unroll
    for (int r = 0; r < 4; ++r) {
      qp[rowoff[0][r]] = (_Float16)(acc0[r] + bias);
      qp[rowoff[1][r]] = (_Float16)(acc1[r] + bias);
    }
  }
}

// K2: per-window attention (all heads) + output projection
__global__ __launch_bounds__(256) void k_attn(
    const _Float16* __restrict__ qkv16, const float* __restrict__ bm,
    const float* __restrict__ logit_scale, const _Float16* __restrict__ W2,
    const float* __restrict__ proj_b, float* __restrict__ out) {
  __shared__ __align__(16) _Float16 qn[64 * 32];
  __shared__ __align__(16) _Float16 kn[64 * 32];
  __shared__ __align__(16) _Float16 vT[32 * 72];   // [d][n], n padded to 72
  __shared__ __align__(16) _Float16 Pl[64 * 72];   // [row][col], col padded
  __shared__ __align__(16) _Float16 ao[64 * 200];  // [row][192], stride 200

  const int b = blockIdx.x;
  const int widx = b & 63;
  const int tid = threadIdx.x;
  const int lane = tid & 63;
  const int w = tid >> 6;
  const int lr = lane & 15;
  const int lg = lane >> 4;
  const int lk = lg * 8;

  // zero qn/kn/vT (padding rows/cols must be exact 0, and no NaN garbage)
  {
    uint32_t* z1 = (uint32_t*)qn;
    uint32_t* z2 = (uint32_t*)kn;
    uint32_t* z3 = (uint32_t*)vT;
    for (int i = tid; i < 1024; i += 256) { z1[i] = 0; z2[i] = 0; }
    for (int i = tid; i < 1152; i += 256) z3[i] = 0;
  }

  float inv_s[4];

  for (int h = 0; h < NH; ++h) {
    __syncthreads();  // protect qn/kn/vT/Pl from previous iteration readers
    size_t base_q = ((size_t)(0 * BATCH + b) * NH + h) * (NTOK * HD);
    size_t base_k = ((size_t)(1 * BATCH + b) * NH + h) * (NTOK * HD);
    size_t base_v = ((size_t)(2 * BATCH + b) * NH + h) * (NTOK * HD);
    if (w == 0) {
      if (lane < NTOK) {
        const f16x8* qp = (const f16x8*)(qkv16 + base_q + lane * HD);
        f16x8 v0 = qp[0], v1 = qp[1], v2 = qp[2], v3 = qp[3];
        float ss = 0.f;
#pragma unroll
        for (int i = 0; i < 8; ++i)
          ss += (float)v0[i] * (float)v0[i] + (float)v1[i] * (float)v1[i] +
                (float)v2[i] * (float)v2[i] + (float)v3[i] * (float)v3[i];
        float inv = rsqrtf(fmaxf(ss, 1e-24f));
        f16x8 o0, o1, o2, o3;
#pragma unroll
        for (int i = 0; i < 8; ++i) {
          o0[i] = (_Float16)((float)v0[i] * inv);
          o1[i] = (_Float16)((float)v1[i] * inv);
          o2[i] = (_Float16)((float)v2[i] * inv);
          o3[i] = (_Float16)((float)v3[i] * inv);
        }
        f16x8* dst = (f16x8*)(qn + lane * HD);
        dst[0] = o0; dst[1] = o1; dst[2] = o2; dst[3] = o3;
      }
    } else if (w == 1) {
      if (lane < NTOK) {
        const f16x8* kp = (const f16x8*)(qkv16 + base_k + lane * HD);
        f16x8 v0 = kp[0], v1 = kp[1], v2 = kp[2], v3 = kp[3];
        float ss = 0.f;
#pragma unroll
        for (int i = 0; i < 8; ++i)
          ss += (float)v0[i] * (float)v0[i] + (float)v1[i] * (float)v1[i] +
                (float)v2[i] * (float)v2[i] + (float)v3[i] * (float)v3[i];
        float inv = rsqrtf(fmaxf(ss, 1e-24f));
        f16x8 o0, o1, o2, o3;
#pragma unroll
        for (int i = 0; i < 8; ++i) {
          o0[i] = (_Float16)((float)v0[i] * inv);
          o1[i] = (_Float16)((float)v1[i] * inv);
          o2[i] = (_Float16)((float)v2[i] * inv);
          o3[i] = (_Float16)((float)v3[i] * inv);
        }
        f16x8* dst = (f16x8*)(kn + lane * HD);
        dst[0] = o0; dst[1] = o1; dst[2] = o2; dst[3] = o3;
      }
    } else {
      int t0 = tid - 128;
      for (int idx = t0; idx < NTOK * HD; idx += 128) {
        int n = idx >> 5, d = idx & 31;
        vT[d * 72 + n] = qkv16[base_v + idx];
      }
    }
    __syncthreads();

    // QK^T: wave w owns rows [16w,16w+16); 4 col tiles
    f16x8 aq = *(const f16x8*)(qn + (w * 16 + lr) * HD + lk);
    float sc = __expf(fminf(logit_scale[h], 4.60517019f));  // min(ls, log 100)
    float p[4][4];
    const float* bmh = bm + (size_t)(widx * NH + h) * 2401;
#pragma unroll
    for (int t = 0; t < 4; ++t) {
      f16x8 bk = *(const f16x8*)(kn + (t * 16 + lr) * HD + lk);
      f32x4 s4 = {0.f, 0.f, 0.f, 0.f};
      s4 = MFMA16(aq, bk, s4);
      int j = t * 16 + lr;
#pragma unroll
      for (int r = 0; r < 4; ++r) {
        int i = w * 16 + lg * 4 + r;
        float val;
        if (j < NTOK && i < NTOK)
          val = s4[r] * sc + bmh[i * 49 + j];
        else
          val = (j >= NTOK) ? -1e30f : 0.0f;
        p[t][r] = val;
      }
    }
    // softmax over rows (row = cols of the 16-lane group, spread over 4 tiles)
#pragma unroll
    for (int r = 0; r < 4; ++r) {
      float m = fmaxf(fmaxf(p[0][r], p[1][r]), fmaxf(p[2][r], p[3][r]));
#pragma unroll
      for (int msk = 1; msk < 16; msk <<= 1) m = fmaxf(m, __shfl_xor(m, msk));
      float sum = 0.f;
#pragma unroll
      for (int t = 0; t < 4; ++t) {
        p[t][r] = __expf(p[t][r] - m);
        sum += p[t][r];
      }
#pragma unroll
      for (int msk = 1; msk < 16; msk <<= 1) sum += __shfl_xor(sum, msk);
      inv_s[r] = 1.0f / sum;  // sum >= 1 always (diagonal)
    }
    // write P (unnormalized; scale applied at PV output)
#pragma unroll
    for (int t = 0; t < 4; ++t)
#pragma unroll
      for (int r = 0; r < 4; ++r)
        Pl[(w * 16 + lg * 4 + r) * 72 + t * 16 + lr] = (_Float16)p[t][r];
    __syncthreads();

    // PV: out[64x32] = P[64x64] * v[64x32]
    f16x8 ap0 = *(const f16x8*)(Pl + (w * 16 + lr) * 72 + lk);
    f16x8 ap1 = *(const f16x8*)(Pl + (w * 16 + lr) * 72 + lk + 32);
#pragma unroll
    for (int td = 0; td < 2; ++td) {
      f16x8 bv0 = *(const f16x8*)(vT + (td * 16 + lr) * 72 + lk);
      f16x8 bv1 = *(const f16x8*)(vT + (td * 16 + lr) * 72 + lk + 32);
      f32x4 o4 = {0.f, 0.f, 0.f, 0.f};
      o4 = MFMA16(ap0, bv0, o4);
      o4 = MFMA16(ap1, bv1, o4);
#pragma unroll
      for (int r = 0; r < 4; ++r) {
        int row = w * 16 + lg * 4 + r;
        ao[row * 200 + h * 32 + td * 16 + lr] = (_Float16)(o4[r] * inv_s[r]);
      }
    }
  }
  __syncthreads();

  // proj: out[49x192] = ao[64x192] @ W2^T + proj_b ; wave w = row-tile w
  f16x8 aa[6];
#pragma unroll
  for (int kf = 0; kf < 6; ++kf)
    aa[kf] = *(const f16x8*)(ao + (w * 16 + lr) * 200 + kf * 32 + lk);
  for (int ct = 0; ct < 12; ++ct) {
    f32x4 acc = {0.f, 0.f, 0.f, 0.f};
    const _Float16* wp = W2 + (ct * 16 + lr) * DIM + lk;
#pragma unroll
    for (int kf = 0; kf < 6; ++kf) {
      f16x8 bw = *(const f16x8*)(wp + kf * 32);
      acc = MFMA16(aa[kf], bw, acc);
    }
    int col = ct * 16 + lr;
    float pb = proj_b[col];
#pragma unroll
    for (int r = 0; r < 4; ++r) {
      int row = w * 16 + lg * 4 + r;
      if (row < NTOK)
        out[((size_t)b * NTOK + row) * DIM + col] = acc[r] + pb;
    }
  }
}

extern "C" void kernel_launch(void* const* d_in, const int* in_sizes, int n_in,
                              void* d_out, int out_size, void* d_ws, size_t ws_size,
                              hipStream_t stream) {
  const float* x     = (const float*)d_in[0];
  const float* mask  = (const float*)d_in[1];
  const float* qkv_w = (const float*)d_in[2];
  const float* qkv_b = (const float*)d_in[3];
  const float* ls    = (const float*)d_in[4];
  const float* tbl   = (const float*)d_in[5];
  const int*   ridx  = (const int*)d_in[6];
  const float* pw    = (const float*)d_in[7];
  const float* pb    = (const float*)d_in[8];
  float* out = (float*)d_out;
  char* ws = (char*)d_ws;

  _Float16* W1 = (_Float16*)(ws + W1_OFF);
  _Float16* W2 = (_Float16*)(ws + W2_OFF);
  float* bm = (float*)(ws + BM_OFF);
  _Float16* qkv16 = (_Float16*)(ws + QKV_OFF);

  hipLaunchKernelGGL(k_setup, dim3(3602), dim3(256), 0, stream,
                     qkv_w, pw, mask, tbl, ridx, W1, W2, bm);
  hipLaunchKernelGGL(k_qkv, dim3(M_TOTAL / 128), dim3(256), 0, stream,
                     x, W1, qkv_b, qkv16);
  hipLaunchKernelGGL(k_attn, dim3(BATCH), dim3(256), 0, stream,
                     qkv16, bm, ls, W2, pb, out);
}

// Round 3
// 563.046 us; speedup vs baseline: 1.2120x; 1.2120x over previous
//
#include <hip/hip_runtime.h>
#include <hip/hip_bf16.h>
#include <hip/hip_fp16.h>

// Swin-V2 window attention, fully fused, MI355X (gfx950).
// K0 setup: f16 weights + transposed f16 (bias+mask) table + per-head scales.
// K1 fused: per-window block = QKV GEMM (f16 MFMA, per-head col slices)
//           -> cosine attn (swapped QK^T, in-register softmax) -> proj.
// LDS = exactly 40960 B -> 4 blocks/CU. All LDS strides 2-way-conflict max.

#define NTOK 49
#define DIM 192
#define NH 6
#define BATCH 4096

typedef __attribute__((ext_vector_type(4))) float f32x4;
typedef __attribute__((ext_vector_type(8))) _Float16 f16x8;

// ws layout (bytes)
#define W1_OFF 0                       // [576][192] f16
#define W2_OFF 221184                  // [192][192] f16
#define BMT_OFF 294912                 // [64][6][49(j)][49(i)] f16 (+slack)
#define HSC_OFF 2139136                // [6] f32 head scales

#define MFMA16(a, b, c) __builtin_amdgcn_mfma_f32_16x16x32_f16(a, b, c, 0, 0, 0)

__global__ __launch_bounds__(256) void k_setup(
    const float* __restrict__ qkv_w, const float* __restrict__ proj_w,
    const float* __restrict__ mask, const float* __restrict__ table,
    const int* __restrict__ rel_index, const float* __restrict__ ls,
    _Float16* __restrict__ W1, _Float16* __restrict__ W2,
    _Float16* __restrict__ bmt, float* __restrict__ hsc) {
  int idx = blockIdx.x * 256 + threadIdx.x;
  if (idx < 576 * 192) W1[idx] = (_Float16)qkv_w[idx];
  if (idx < 192 * 192) W2[idx] = (_Float16)proj_w[idx];
  if (idx < NH) hsc[idx] = __expf(fminf(ls[idx], 4.60517019f));
  if (idx < 64 * NH * 2401) {
    int p = idx / 2401, rem = idx % 2401;
    int j = rem / 49, i = rem % 49;       // stored [p][j][i] (transposed)
    int wdx = p / NH, h = p % NH;
    bmt[idx] = (_Float16)(table[rel_index[i * 49 + j] * NH + h] +
                          mask[wdx * 2401 + i * 49 + j]);
  }
}

__global__ __launch_bounds__(256, 4) void k_fused(
    const float* __restrict__ x, const _Float16* __restrict__ W1,
    const float* __restrict__ qkv_b, const _Float16* __restrict__ bmt,
    const float* __restrict__ hsc, const _Float16* __restrict__ W2,
    const float* __restrict__ proj_b, float* __restrict__ out) {
  __shared__ __align__(16) char smem[40960];
  _Float16* qh = (_Float16*)smem;            // [64][40] f16
  _Float16* kh = (_Float16*)(smem + 5120);   // [64][40] f16
  _Float16* Pl = (_Float16*)smem;            // [64][72] f16, aliases qh/kh
  _Float16* vT = (_Float16*)(smem + 10240);  // [32][72] f16 (v transposed)
  _Float16* ao = (_Float16*)(smem + 14848);  // [64][200] f16
  float* qrs = (float*)(smem + 40448);       // [64] rsqrt(|q|^2)*scale
  float* krs = (float*)(smem + 40704);       // [64] rsqrt(|k|^2)

  const int b = blockIdx.x;
  const int tid = threadIdx.x;
  const int lane = tid & 63;
  const int w = tid >> 6;   // wave id = M row-tile
  const int L = lane & 15;
  const int g = lane >> 4;
  const int plane_base = (b & 63) * NH;
  const f32x4 vzero = {0.f, 0.f, 0.f, 0.f};

  // ---- x A-fragments: rows 16w+L (zero past 49), k = 32kf + 8g .. +8 ----
  f16x8 ax[6];
  {
    const int row = 16 * w + L;
    const float* xr = x + ((size_t)b * NTOK + (row < NTOK ? row : 0)) * DIM + 8 * g;
#pragma unroll
    for (int kf = 0; kf < 6; ++kf) {
      f32x4 lo = *(const f32x4*)(xr + 32 * kf);
      f32x4 hi = *(const f32x4*)(xr + 32 * kf + 4);
      if (row >= NTOK) { lo = vzero; hi = vzero; }
      f16x8 v;
      v[0] = (_Float16)lo[0]; v[1] = (_Float16)lo[1];
      v[2] = (_Float16)lo[2]; v[3] = (_Float16)lo[3];
      v[4] = (_Float16)hi[0]; v[5] = (_Float16)hi[1];
      v[6] = (_Float16)hi[2]; v[7] = (_Float16)hi[3];
      ax[kf] = v;
    }
  }

#pragma unroll 1
  for (int h = 0; h < NH; ++h) {
    __syncthreads();  // prev head's Pl/vT readers done before overwrite
    const float hs = hsc[h];

    // ---- per-head QKV GEMM: q->qh, k->kh, v->vT(transposed) ----
    float ssq[4] = {0.f, 0.f, 0.f, 0.f}, ssk[4] = {0.f, 0.f, 0.f, 0.f};
#pragma unroll
    for (int s = 0; s < 3; ++s) {
#pragma unroll
      for (int ct = 0; ct < 2; ++ct) {
        const int col = s * DIM + 32 * h + 16 * ct + L;
        const _Float16* wp = W1 + (size_t)col * DIM + 8 * g;
        f32x4 acc = {0.f, 0.f, 0.f, 0.f};
#pragma unroll
        for (int kf = 0; kf < 6; ++kf)
          acc = MFMA16(ax[kf], *(const f16x8*)(wp + 32 * kf), acc);
        const float bias = qkv_b[col];
#pragma unroll
        for (int r = 0; r < 4; ++r) {
          float v = acc[r] + bias;
          if (s == 0) {
            qh[(16 * w + 4 * g + r) * 40 + 16 * ct + L] = (_Float16)v;
            ssq[r] += v * v;
          } else if (s == 1) {
            kh[(16 * w + 4 * g + r) * 40 + 16 * ct + L] = (_Float16)v;
            ssk[r] += v * v;
          } else {
            vT[(16 * ct + L) * 72 + 16 * w + 4 * g + r] = (_Float16)v;
          }
        }
      }
      if (s == 0) {
#pragma unroll
        for (int r = 0; r < 4; ++r) {
          float ss = ssq[r];
          ss += __shfl_xor(ss, 1); ss += __shfl_xor(ss, 2);
          ss += __shfl_xor(ss, 4); ss += __shfl_xor(ss, 8);
          if (L == 0) qrs[16 * w + 4 * g + r] = rsqrtf(fmaxf(ss, 1e-24f)) * hs;
        }
      } else if (s == 1) {
#pragma unroll
        for (int r = 0; r < 4; ++r) {
          float ss = ssk[r];
          ss += __shfl_xor(ss, 1); ss += __shfl_xor(ss, 2);
          ss += __shfl_xor(ss, 4); ss += __shfl_xor(ss, 8);
          if (L == 0) krs[16 * w + 4 * g + r] = rsqrtf(fmaxf(ss, 1e-24f));
        }
      }
    }
    __syncthreads();  // A: qh/kh/vT/qrs/krs visible to all waves

    // ---- S^T = K·Q : D col = i (16w+L), D row = j (16t+4g+r) ----
    // early bias+mask loads (hide L2 latency under MFMAs)
    const _Float16* bp = bmt + (size_t)(plane_base + h) * 2401 + 16 * w + L;
    _Float16 bm16[4][4];
#pragma unroll
    for (int t = 0; t < 4; ++t)
#pragma unroll
      for (int r = 0; r < 4; ++r) {
        int j = 16 * t + 4 * g + r;
        bm16[t][r] = bp[(j < NTOK ? j : NTOK - 1) * NTOK];
      }
    f16x8 bq = *(const f16x8*)(qh + (16 * w + L) * 40 + 8 * g);
    f32x4 st[4];
#pragma unroll
    for (int t = 0; t < 4; ++t) {
      f16x8 ak = *(const f16x8*)(kh + (16 * t + L) * 40 + 8 * g);
      f32x4 z = {0.f, 0.f, 0.f, 0.f};
      st[t] = MFMA16(ak, bq, z);
    }
    const float qr = qrs[16 * w + L];
    __syncthreads();  // B: all qh/kh reads done; qh/kh area becomes Pl

    // ---- softmax over j, fully in-register ----
    float p[4][4];
#pragma unroll
    for (int t = 0; t < 4; ++t)
#pragma unroll
      for (int r = 0; r < 4; ++r) {
        int j = 16 * t + 4 * g + r;
        p[t][r] = (j < NTOK)
                      ? fmaf(st[t][r], qr * krs[j], (float)bm16[t][r])
                      : -1e30f;
      }
    float mx = p[0][0];
#pragma unroll
    for (int t = 0; t < 4; ++t)
#pragma unroll
      for (int r = 0; r < 4; ++r) mx = fmaxf(mx, p[t][r]);
    mx = fmaxf(mx, __shfl_xor(mx, 16));
    mx = fmaxf(mx, __shfl_xor(mx, 32));
    float sum = 0.f;
#pragma unroll
    for (int t = 0; t < 4; ++t)
#pragma unroll
      for (int r = 0; r < 4; ++r) {
        p[t][r] = __expf(p[t][r] - mx);
        sum += p[t][r];
      }
    sum += __shfl_xor(sum, 16);
    sum += __shfl_xor(sum, 32);
    const float is = 1.0f / sum;

    // write normalized P (f16) to own rows of Pl
    _Float16* pr = Pl + (16 * w + L) * 72;
#pragma unroll
    for (int t = 0; t < 4; ++t) {
#pragma unroll
      for (int r = 0; r < 4; ++r)
        pr[16 * t + 4 * g + r] = (_Float16)(p[t][r] * is);
    }

    // ---- PV: O[i][d] = sum_j P[i][j] vT[d][j] (same-wave LDS RAW) ----
    f16x8 pa0 = *(const f16x8*)(pr + 8 * g);
    f16x8 pa1 = *(const f16x8*)(pr + 32 + 8 * g);
#pragma unroll
    for (int dt = 0; dt < 2; ++dt) {
      f16x8 bv0 = *(const f16x8*)(vT + (16 * dt + L) * 72 + 8 * g);
      f16x8 bv1 = *(const f16x8*)(vT + (16 * dt + L) * 72 + 32 + 8 * g);
      f32x4 o4 = {0.f, 0.f, 0.f, 0.f};
      o4 = MFMA16(pa0, bv0, o4);
      o4 = MFMA16(pa1, bv1, o4);
#pragma unroll
      for (int r = 0; r < 4; ++r)
        ao[(16 * w + 4 * g + r) * 200 + 32 * h + 16 * dt + L] = (_Float16)o4[r];
    }
  }

  // ---- proj: out = ao @ W2^T + b (ao rows are wave-private) ----
  f16x8 aa[6];
#pragma unroll
  for (int kf = 0; kf < 6; ++kf)
    aa[kf] = *(const f16x8*)(ao + (16 * w + L) * 200 + 32 * kf + 8 * g);
#pragma unroll 1
  for (int ct = 0; ct < 12; ++ct) {
    const _Float16* wp = W2 + (size_t)(16 * ct + L) * DIM + 8 * g;
    f32x4 acc = {0.f, 0.f, 0.f, 0.f};
#pragma unroll
    for (int kf = 0; kf < 6; ++kf)
      acc = MFMA16(aa[kf], *(const f16x8*)(wp + 32 * kf), acc);
    const float pb = proj_b[16 * ct + L];
#pragma unroll
    for (int r = 0; r < 4; ++r) {
      int row = 16 * w + 4 * g + r;
      if (row < NTOK)
        out[((size_t)b * NTOK + row) * DIM + 16 * ct + L] = acc[r] + pb;
    }
  }
}

extern "C" void kernel_launch(void* const* d_in, const int* in_sizes, int n_in,
                              void* d_out, int out_size, void* d_ws, size_t ws_size,
                              hipStream_t stream) {
  const float* x     = (const float*)d_in[0];
  const float* mask  = (const float*)d_in[1];
  const float* qkv_w = (const float*)d_in[2];
  const float* qkv_b = (const float*)d_in[3];
  const float* ls    = (const float*)d_in[4];
  const float* tbl   = (const float*)d_in[5];
  const int*   ridx  = (const int*)d_in[6];
  const float* pw    = (const float*)d_in[7];
  const float* pb    = (const float*)d_in[8];
  float* out = (float*)d_out;
  char* ws = (char*)d_ws;

  _Float16* W1 = (_Float16*)(ws + W1_OFF);
  _Float16* W2 = (_Float16*)(ws + W2_OFF);
  _Float16* bmt = (_Float16*)(ws + BMT_OFF);
  float* hsc = (float*)(ws + HSC_OFF);

  hipLaunchKernelGGL(k_setup, dim3(3602), dim3(256), 0, stream,
                     qkv_w, pw, mask, tbl, ridx, ls, W1, W2, bmt, hsc);
  hipLaunchKernelGGL(k_fused, dim3(BATCH), dim3(256), 0, stream,
                     x, W1, qkv_b, bmt, hsc, W2, pb, out);
}